// Round 2
// baseline (4166.339 us; speedup 1.0000x reference)
//
#include <hip/hip_runtime.h>
#include <hip/hip_bf16.h>
#include <stdint.h>

#define HID    128
#define DT     0.1f
#define NITER  10
#define RT     64          // rows (b,q pairs) per block
#define NT     256         // threads per block
#define HP     (HID + 4)   // padded row stride for H tiles

struct alignas(16) Smem {
    uint32_t w2[HID * HID / 2];   // bf16 pairs (converted from fp32 at stage)
    uint32_t w3[HID * HID / 2];   // bf16 pairs
    float    hA[RT * HP];
    float    hB[RT * HP];
    float    w1[4 * HID];
    float    w4[HID * 4];
    float    b1[HID];
    float    b2[HID];
    float    b3[HID];
    float    b4[4];
    float    alpha[16];
    float    beta[4];
    float    lam[4];
    float    x0[RT * 4];
    float    x[RT * 4];
    float    kk[RT * 4];
    float    hout[RT * 4];
};

__device__ __forceinline__ uint32_t f2bf_rn(float f) {
    uint32_t u = __float_as_uint(f);
    return (u + 0x7fffu + ((u >> 16) & 1u)) >> 16;   // round-to-nearest-even bf16
}

__device__ __forceinline__ float fast_tanh(float x) {
    float xc = fminf(fmaxf(x, -9.0f), 9.0f);
    float e  = __expf(2.0f * xc);
    return (e - 1.0f) / (e + 1.0f);
}

// H_dst[64][HID] = tanh(H_src[64][HID] @ W[HID][HID] + bias), W as bf16 pairs.
// Thread tile: 4 rows x 8 cols. rg in [0,16), cg in [0,16).
__device__ __forceinline__ void dense128(const uint32_t* __restrict__ wu,
                                         const float* __restrict__ bias,
                                         const float* __restrict__ src,
                                         float* __restrict__ dst,
                                         int rg, int cg)
{
    float acc[4][8];
    #pragma unroll
    for (int a = 0; a < 4; ++a)
        #pragma unroll
        for (int b = 0; b < 8; ++b) acc[a][b] = 0.0f;

    const float* s0 = src + (rg * 4 + 0) * HP;
    const float* s1 = src + (rg * 4 + 1) * HP;
    const float* s2 = src + (rg * 4 + 2) * HP;
    const float* s3 = src + (rg * 4 + 3) * HP;
    const uint32_t* wp = wu + cg * 4;

    #pragma unroll 2
    for (int k4 = 0; k4 < HID / 4; ++k4) {
        float h0[4], h1[4], h2[4], h3[4];
        *reinterpret_cast<float4*>(h0) = *reinterpret_cast<const float4*>(s0 + k4 * 4);
        *reinterpret_cast<float4*>(h1) = *reinterpret_cast<const float4*>(s1 + k4 * 4);
        *reinterpret_cast<float4*>(h2) = *reinterpret_cast<const float4*>(s2 + k4 * 4);
        *reinterpret_cast<float4*>(h3) = *reinterpret_cast<const float4*>(s3 + k4 * 4);
        #pragma unroll
        for (int dk = 0; dk < 4; ++dk) {
            int k = k4 * 4 + dk;
            uint4 wv = *reinterpret_cast<const uint4*>(wp + k * (HID / 2));
            float w[8];
            w[0] = __uint_as_float(wv.x << 16);
            w[1] = __uint_as_float(wv.x & 0xffff0000u);
            w[2] = __uint_as_float(wv.y << 16);
            w[3] = __uint_as_float(wv.y & 0xffff0000u);
            w[4] = __uint_as_float(wv.z << 16);
            w[5] = __uint_as_float(wv.z & 0xffff0000u);
            w[6] = __uint_as_float(wv.w << 16);
            w[7] = __uint_as_float(wv.w & 0xffff0000u);
            #pragma unroll
            for (int b = 0; b < 8; ++b) {
                acc[0][b] = fmaf(h0[dk], w[b], acc[0][b]);
                acc[1][b] = fmaf(h1[dk], w[b], acc[1][b]);
                acc[2][b] = fmaf(h2[dk], w[b], acc[2][b]);
                acc[3][b] = fmaf(h3[dk], w[b], acc[3][b]);
            }
        }
    }
    #pragma unroll
    for (int a = 0; a < 4; ++a) {
        float* d = dst + (rg * 4 + a) * HP + cg * 8;
        #pragma unroll
        for (int b = 0; b < 8; ++b)
            d[b] = fast_tanh(acc[a][b] + bias[cg * 8 + b]);
    }
}

__global__ __launch_bounds__(NT, 1) void pinn_irk_kernel(
    const float* __restrict__ x0g,
    const float* __restrict__ w1g,
    const float* __restrict__ b1g,
    const float* __restrict__ w2g,
    const float* __restrict__ b2g,
    const float* __restrict__ w3g,
    const float* __restrict__ b3g,
    const float* __restrict__ w4g,
    const float* __restrict__ b4g,
    const float* __restrict__ l1g,
    const float* __restrict__ l2g,
    const float* __restrict__ l3g,
    const float* __restrict__ l4g,
    const float* __restrict__ alg,
    const float* __restrict__ beg,
    float* __restrict__ outg)
{
    extern __shared__ char smem_raw[];
    Smem& S = *reinterpret_cast<Smem*>(smem_raw);
    const int t   = threadIdx.x;
    const int blk = blockIdx.x;

    // ---- stage weights / params (fp32 inputs; W2/W3 converted to bf16 pairs) ----
    for (int i = t; i < HID * HID / 2; i += NT) {
        float2 a2 = reinterpret_cast<const float2*>(w2g)[i];
        float2 a3 = reinterpret_cast<const float2*>(w3g)[i];
        S.w2[i] = f2bf_rn(a2.x) | (f2bf_rn(a2.y) << 16);
        S.w3[i] = f2bf_rn(a3.x) | (f2bf_rn(a3.y) << 16);
    }
    for (int i = t; i < 4 * HID; i += NT) S.w1[i] = w1g[i];
    for (int i = t; i < HID * 4; i += NT) S.w4[i] = w4g[i];
    if (t < HID) {
        S.b1[t] = b1g[t];
        S.b2[t] = b2g[t];
        S.b3[t] = b3g[t];
    }
    if (t < 16) S.alpha[t] = alg[t];
    if (t < 4)  { S.b4[t] = b4g[t]; S.beta[t] = beg[t]; }
    if (t == 0) {
        S.lam[0] = l1g[0]; S.lam[1] = l2g[0];
        S.lam[2] = l3g[0]; S.lam[3] = l4g[0];
    }
    // X0 tile (duplicated per stage) + K init. t = r*4 + i
    {
        int r = t >> 2, i = t & 3;
        int bglob = blk * (RT / 4) + (r >> 2);
        S.x0[t] = x0g[bglob * 4 + i];
        S.kk[t] = 0.0f;
    }
    __syncthreads();

    const int rg = t >> 4, cg = t & 15;

    for (int it = 0; it < NITER; ++it) {
        // ---- X update: X[r][j] = X0[r][j] + dt * sum_i K[r][i]*alpha[i][j] ----
        {
            int r = t >> 2, j = t & 3;
            float s = 0.0f;
            #pragma unroll
            for (int i = 0; i < 4; ++i) s += S.kk[r * 4 + i] * S.alpha[i * 4 + j];
            S.x[t] = S.x0[t] + DT * s;
        }
        __syncthreads();

        // ---- layer 1: (64x4) @ (4x128) + b1, tanh -> hA ----
        {
            float acc[4][8];
            #pragma unroll
            for (int a = 0; a < 4; ++a)
                #pragma unroll
                for (int b = 0; b < 8; ++b) acc[a][b] = S.b1[cg * 8 + b];
            #pragma unroll
            for (int i = 0; i < 4; ++i) {
                float w[8];
                #pragma unroll
                for (int b = 0; b < 8; ++b) w[b] = S.w1[i * HID + cg * 8 + b];
                #pragma unroll
                for (int a = 0; a < 4; ++a) {
                    float xv = S.x[(rg * 4 + a) * 4 + i];
                    #pragma unroll
                    for (int b = 0; b < 8; ++b) acc[a][b] = fmaf(xv, w[b], acc[a][b]);
                }
            }
            #pragma unroll
            for (int a = 0; a < 4; ++a)
                #pragma unroll
                for (int b = 0; b < 8; ++b)
                    S.hA[(rg * 4 + a) * HP + cg * 8 + b] = fast_tanh(acc[a][b]);
        }
        __syncthreads();

        // ---- layer 2: hB = tanh(hA @ W2 + b2) ----
        dense128(S.w2, S.b2, S.hA, S.hB, rg, cg);
        __syncthreads();

        // ---- layer 3: hA = tanh(hB @ W3 + b3) ----
        dense128(S.w3, S.b3, S.hB, S.hA, rg, cg);
        __syncthreads();

        // ---- layer 4: hout[r][o] = hA[r][:] @ W4[:,o] + b4[o]. t = r*4 + o ----
        {
            int r = t >> 2, o = t & 3;
            float s = S.b4[o];
            const float* h = S.hA + r * HP;
            #pragma unroll 8
            for (int k = 0; k < HID; ++k) s = fmaf(h[k], S.w4[k * 4 + o], s);
            S.hout[t] = s;
        }
        __syncthreads();

        // ---- K update (hamiltonian vf). t = r*4 + c; component index map c^2 ----
        {
            int r = t >> 2, c = t & 3;
            int idx = c ^ 2;
            float Hv = S.hout[r * 4 + idx];
            float Xv = S.x[r * 4 + idx];
            float kv;
            if (c < 2) kv = -S.lam[0] * Hv - S.lam[1] * Xv;   // dp/dt
            else       kv =  S.lam[2] * Hv + S.lam[3] * Xv;   // dq/dt
            S.kk[t] = kv;
        }
        __syncthreads();
    }

    // ---- final combine: X1[b][i] = X0[b][i] + dt * sum_q beta[q]*K[b,q,i] ----
    if (t < RT) {
        int bb = t >> 2, i = t & 3;
        float s = 0.0f;
        #pragma unroll
        for (int q = 0; q < 4; ++q) s += S.beta[q] * S.kk[(bb * 4 + q) * 4 + i];
        float v = S.x0[(bb * 4) * 4 + i] + DT * s;
        outg[(blk * (RT / 4) + bb) * 4 + i] = v;
    }
}

extern "C" void kernel_launch(void* const* d_in, const int* in_sizes, int n_in,
                              void* d_out, int out_size, void* d_ws, size_t ws_size,
                              hipStream_t stream) {
    (void)in_sizes; (void)n_in; (void)d_ws; (void)ws_size; (void)out_size;

    hipFuncSetAttribute(reinterpret_cast<const void*>(pinn_irk_kernel),
                        hipFuncAttributeMaxDynamicSharedMemorySize,
                        (int)sizeof(Smem));

    const int n_rows = 65536 * 4;           // B * Q
    dim3 grid(n_rows / RT);                 // 4096
    dim3 block(NT);

    pinn_irk_kernel<<<grid, block, sizeof(Smem), stream>>>(
        (const float*)d_in[0],   // X0
        (const float*)d_in[1],   // W1
        (const float*)d_in[2],   // b1
        (const float*)d_in[3],   // W2
        (const float*)d_in[4],   // b2
        (const float*)d_in[5],   // W3
        (const float*)d_in[6],   // b3
        (const float*)d_in[7],   // W4
        (const float*)d_in[8],   // b4
        (const float*)d_in[9],   // lam1
        (const float*)d_in[10],  // lam2
        (const float*)d_in[11],  // lam3
        (const float*)d_in[12],  // lam4
        (const float*)d_in[13],  // IRK_alpha
        (const float*)d_in[14],  // IRK_beta
        (float*)d_out);
}

// Round 3
// 790.860 us; speedup vs baseline: 5.2681x; 5.2681x over previous
//
#include <hip/hip_runtime.h>
#include <stdint.h>

#define HID   128
#define DT    0.1f
#define NITER 10
#define RT    64           // rows (b,q pairs) per block
#define NT    256          // 4 waves
#define HSTR  136          // H row stride in bf16 elems (128 + 8 pad; odd multiple of 16B)

typedef __attribute__((ext_vector_type(8))) short bf16x8;   // MFMA A/B frag (4 VGPRs)
typedef __attribute__((ext_vector_type(4))) float f32x4;    // MFMA C/D frag
typedef __attribute__((ext_vector_type(2))) unsigned int u32x2;

struct alignas(16) Smem {
    uint16_t hA[RT * HSTR];   // activations, [batch][hid] bf16
    uint16_t hB[RT * HSTR];
    uint16_t xb[RT * 8];      // X in bf16, [row][8] (cols 4..7 zero)
    float b1[HID], b2[HID], b3[HID];
    float b4[4];
    float alpha[16];
    float beta[4];
    float lam[4];
    float x0[RT * 4];
    float x[RT * 4];
    float kk[RT * 4];
};

__device__ __forceinline__ uint16_t f2bf(float f) {
    uint32_t u = __float_as_uint(f);
    return (uint16_t)((u + 0x7fffu + ((u >> 16) & 1u)) >> 16);
}

// tanh = 1 - 2/(e^{2x}+1); robust for +/-inf inputs, 2 quarter-rate ops.
__device__ __forceinline__ float tanh_fast(float x) {
    float e = __builtin_amdgcn_exp2f(x * 2.885390081777927f);  // e^{2x}
    return fmaf(-2.0f, __builtin_amdgcn_rcpf(e + 1.0f), 1.0f);
}

// One 128->128 dense layer, transposed MFMA: G^T = W^T H^T.
// wf[mt][kt] = A-frags of W^T (in registers); src/dst = [batch][hid] bf16 in LDS.
__device__ __forceinline__ void dense_mfma(
    const bf16x8 (&wf)[4][4], const float* __restrict__ bias,
    const uint16_t* __restrict__ src, uint16_t* __restrict__ dst,
    int wm, int wn, int ln, int g)
{
    f32x4 acc[4][2];
    #pragma unroll
    for (int mt = 0; mt < 4; ++mt)
        #pragma unroll
        for (int nt = 0; nt < 2; ++nt) acc[mt][nt] = (f32x4){0.f, 0.f, 0.f, 0.f};

    const int r0 = wn * 32 + ln;
    const int r1 = r0 + 16;

    #pragma unroll
    for (int kt = 0; kt < 4; ++kt) {
        bf16x8 bfr0 = *(const bf16x8*)&src[r0 * HSTR + kt * 32 + 8 * g];
        bf16x8 bfr1 = *(const bf16x8*)&src[r1 * HSTR + kt * 32 + 8 * g];
        #pragma unroll
        for (int mt = 0; mt < 4; ++mt) {
            acc[mt][0] = __builtin_amdgcn_mfma_f32_16x16x32_bf16(wf[mt][kt], bfr0, acc[mt][0], 0, 0, 0);
            acc[mt][1] = __builtin_amdgcn_mfma_f32_16x16x32_bf16(wf[mt][kt], bfr1, acc[mt][1], 0, 0, 0);
        }
    }
    #pragma unroll
    for (int mt = 0; mt < 4; ++mt) {
        int hb = wm * 64 + mt * 16 + 4 * g;         // 4 consecutive hid per lane
        f32x4 bs = *(const f32x4*)&bias[hb];
        #pragma unroll
        for (int nt = 0; nt < 2; ++nt) {
            int r = wn * 32 + nt * 16 + ln;
            uint32_t p0 = (uint32_t)f2bf(tanh_fast(acc[mt][nt][0] + bs[0]))
                        | ((uint32_t)f2bf(tanh_fast(acc[mt][nt][1] + bs[1])) << 16);
            uint32_t p1 = (uint32_t)f2bf(tanh_fast(acc[mt][nt][2] + bs[2]))
                        | ((uint32_t)f2bf(tanh_fast(acc[mt][nt][3] + bs[3])) << 16);
            *(u32x2*)&dst[r * HSTR + hb] = (u32x2){p0, p1};
        }
    }
}

__global__ __launch_bounds__(NT, 2) void pinn_irk_mfma(
    const float* __restrict__ x0g,
    const float* __restrict__ w1g, const float* __restrict__ b1g,
    const float* __restrict__ w2g, const float* __restrict__ b2g,
    const float* __restrict__ w3g, const float* __restrict__ b3g,
    const float* __restrict__ w4g, const float* __restrict__ b4g,
    const float* __restrict__ l1g, const float* __restrict__ l2g,
    const float* __restrict__ l3g, const float* __restrict__ l4g,
    const float* __restrict__ alg, const float* __restrict__ beg,
    float* __restrict__ outg)
{
    __shared__ Smem S;
    const int t    = threadIdx.x;
    const int blk  = blockIdx.x;
    const int lane = t & 63;
    const int w    = t >> 6;        // wave 0..3
    const int wm   = w & 1;         // hid half (M)
    const int wn   = w >> 1;        // batch half (N)
    const int ln   = lane & 15;
    const int g    = lane >> 4;     // quad

    // ---- stage params ----
    if (t < HID) { S.b1[t] = b1g[t]; S.b2[t] = b2g[t]; S.b3[t] = b3g[t]; }
    if (t < 16) S.alpha[t] = alg[t];
    if (t < 4)  { S.b4[t] = b4g[t]; S.beta[t] = beg[t]; }
    if (t == 0) { S.lam[0] = l1g[0]; S.lam[1] = l2g[0]; S.lam[2] = l3g[0]; S.lam[3] = l4g[0]; }
    {
        int r = t >> 2, i = t & 3;
        int bglob = blk * (RT / 4) + (r >> 2);
        S.x0[r * 4 + i] = x0g[bglob * 4 + i];
        S.kk[r * 4 + i] = 0.0f;
    }
    for (int i = t; i < RT * 8; i += NT) S.xb[i] = 0;

    // ---- load weight fragments into registers (one-time) ----
    // A-frag of W^T: lane (ln,g), elem j -> W[k = kt*32+8g+j][m = wm*64+mt*16+ln]
    bf16x8 w1f[4], w2f[4][4], w3f[4][4], w4f[4];
    {
        const int mcol = wm * 64 + ln;
        #pragma unroll
        for (int mt = 0; mt < 4; ++mt) {
            bf16x8 f1;
            #pragma unroll
            for (int j = 0; j < 8; ++j) {
                int k = 8 * g + j;
                float v = (k < 4) ? w1g[k * HID + mcol + mt * 16] : 0.0f;
                f1[j] = (short)f2bf(v);
            }
            w1f[mt] = f1;
            #pragma unroll
            for (int kt = 0; kt < 4; ++kt) {
                bf16x8 f2, f3;
                #pragma unroll
                for (int j = 0; j < 8; ++j) {
                    int k = kt * 32 + 8 * g + j;
                    f2[j] = (short)f2bf(w2g[k * HID + mcol + mt * 16]);
                    f3[j] = (short)f2bf(w3g[k * HID + mcol + mt * 16]);
                }
                w2f[mt][kt] = f2;
                w3f[mt][kt] = f3;
            }
        }
        #pragma unroll
        for (int kt = 0; kt < 4; ++kt) {
            bf16x8 f4;
            #pragma unroll
            for (int j = 0; j < 8; ++j) {
                int k = kt * 32 + 8 * g + j;
                float v = (ln < 4) ? w4g[k * 4 + ln] : 0.0f;   // W4^T[m=o][k]
                f4[j] = (short)f2bf(v);
            }
            w4f[kt] = f4;
        }
    }
    __syncthreads();

    const float L0 = S.lam[0], L1_ = S.lam[1], L2_ = S.lam[2], L3_ = S.lam[3];

    #pragma unroll 1
    for (int it = 0; it < NITER; ++it) {
        // ---- X update: X[r][c] = X0[r][c] + dt * sum_i K[r][i]*alpha[i][c] ----
        {
            int r = t >> 2, c = t & 3;
            f32x4 kv = *(const f32x4*)&S.kk[r * 4];
            float s = kv[0] * S.alpha[c] + kv[1] * S.alpha[4 + c]
                    + kv[2] * S.alpha[8 + c] + kv[3] * S.alpha[12 + c];
            float xv = S.x0[r * 4 + c] + DT * s;
            S.x[r * 4 + c] = xv;
            S.xb[r * 8 + c] = f2bf(xv);
        }
        __syncthreads();

        // ---- L1: hA = tanh(X @ W1 + b1), via MFMA with K padded 4->32 ----
        {
            f32x4 acc[4][2];
            #pragma unroll
            for (int mt = 0; mt < 4; ++mt) { acc[mt][0] = (f32x4){0,0,0,0}; acc[mt][1] = (f32x4){0,0,0,0}; }
            bf16x8 bfr0 = {0,0,0,0,0,0,0,0}, bfr1 = {0,0,0,0,0,0,0,0};
            if (g == 0) {
                bfr0 = *(const bf16x8*)&S.xb[(wn * 32 + ln) * 8];
                bfr1 = *(const bf16x8*)&S.xb[(wn * 32 + 16 + ln) * 8];
            }
            #pragma unroll
            for (int mt = 0; mt < 4; ++mt) {
                acc[mt][0] = __builtin_amdgcn_mfma_f32_16x16x32_bf16(w1f[mt], bfr0, acc[mt][0], 0, 0, 0);
                acc[mt][1] = __builtin_amdgcn_mfma_f32_16x16x32_bf16(w1f[mt], bfr1, acc[mt][1], 0, 0, 0);
            }
            #pragma unroll
            for (int mt = 0; mt < 4; ++mt) {
                int hb = wm * 64 + mt * 16 + 4 * g;
                f32x4 bs = *(const f32x4*)&S.b1[hb];
                #pragma unroll
                for (int nt = 0; nt < 2; ++nt) {
                    int r = wn * 32 + nt * 16 + ln;
                    uint32_t p0 = (uint32_t)f2bf(tanh_fast(acc[mt][nt][0] + bs[0]))
                                | ((uint32_t)f2bf(tanh_fast(acc[mt][nt][1] + bs[1])) << 16);
                    uint32_t p1 = (uint32_t)f2bf(tanh_fast(acc[mt][nt][2] + bs[2]))
                                | ((uint32_t)f2bf(tanh_fast(acc[mt][nt][3] + bs[3])) << 16);
                    *(u32x2*)&S.hA[r * HSTR + hb] = (u32x2){p0, p1};
                }
            }
        }
        __syncthreads();

        // ---- L2: hB = tanh(hA @ W2 + b2) ----
        dense_mfma(w2f, S.b2, S.hA, S.hB, wm, wn, ln, g);
        __syncthreads();

        // ---- L3: hA = tanh(hB @ W3 + b3) ----
        dense_mfma(w3f, S.b3, S.hB, S.hA, wm, wn, ln, g);
        __syncthreads();

        // ---- L4 (+K update): hout = hA @ W4 + b4; wave w owns batch tile w ----
        {
            f32x4 acc = (f32x4){0,0,0,0};
            int r = w * 16 + ln;
            #pragma unroll
            for (int kt = 0; kt < 4; ++kt) {
                bf16x8 b = *(const bf16x8*)&S.hA[r * HSTR + kt * 32 + 8 * g];
                acc = __builtin_amdgcn_mfma_f32_16x16x32_bf16(w4f[kt], b, acc, 0, 0, 0);
            }
            if (g == 0) {   // quad 0 holds outs o=0..3 for batch row r
                f32x4 b4v = *(const f32x4*)&S.b4[0];
                float h0 = acc[0] + b4v[0], h1 = acc[1] + b4v[1];
                float h2 = acc[2] + b4v[2], h3 = acc[3] + b4v[3];
                f32x4 xq = *(const f32x4*)&S.x[r * 4];
                f32x4 kv;
                kv[0] = -L0 * h2 - L1_ * xq[2];
                kv[1] = -L0 * h3 - L1_ * xq[3];
                kv[2] =  L2_ * h0 + L3_ * xq[0];
                kv[3] =  L2_ * h1 + L3_ * xq[1];
                *(f32x4*)&S.kk[r * 4] = kv;
            }
        }
        __syncthreads();
    }

    // ---- final combine: X1 = X0 + dt * sum_q beta_q K ----
    if (t < RT) {
        int bb = t >> 2, i = t & 3;
        float s = 0.0f;
        #pragma unroll
        for (int q = 0; q < 4; ++q) s += S.beta[q] * S.kk[(bb * 4 + q) * 4 + i];
        outg[(blk * (RT / 4) + bb) * 4 + i] = S.x0[(bb * 4) * 4 + i] + DT * s;
    }
}

extern "C" void kernel_launch(void* const* d_in, const int* in_sizes, int n_in,
                              void* d_out, int out_size, void* d_ws, size_t ws_size,
                              hipStream_t stream) {
    (void)in_sizes; (void)n_in; (void)d_ws; (void)ws_size; (void)out_size;

    const int n_rows = 65536 * 4;        // B * Q
    dim3 grid(n_rows / RT);              // 4096
    dim3 block(NT);

    pinn_irk_mfma<<<grid, block, 0, stream>>>(
        (const float*)d_in[0],
        (const float*)d_in[1],  (const float*)d_in[2],
        (const float*)d_in[3],  (const float*)d_in[4],
        (const float*)d_in[5],  (const float*)d_in[6],
        (const float*)d_in[7],  (const float*)d_in[8],
        (const float*)d_in[9],  (const float*)d_in[10],
        (const float*)d_in[11], (const float*)d_in[12],
        (const float*)d_in[13], (const float*)d_in[14],
        (float*)d_out);
}

// Round 4
// 617.353 us; speedup vs baseline: 6.7487x; 1.2810x over previous
//
#include <hip/hip_runtime.h>
#include <hip/hip_bf16.h>
#include <stdint.h>

#define HID   128
#define DT    0.1f
#define NITER 10
#define RT    64           // rows (b,q pairs) per block
#define NT    256          // 4 waves
#define HSTR  136          // H row stride in bf16 elems (odd multiple of 16B)

typedef __attribute__((ext_vector_type(8))) short bf16x8;   // MFMA A/B frag
typedef __attribute__((ext_vector_type(4))) float f32x4;    // MFMA C/D frag
typedef __attribute__((ext_vector_type(2))) unsigned int u32x2;
typedef __attribute__((ext_vector_type(4))) unsigned int u32x4;

struct alignas(16) Smem {
    uint16_t hA[RT * HSTR];     // activations [batch][hid] bf16
    uint16_t hB[RT * HSTR];
    uint16_t xb[RT * 8];        // X bf16 [row][8], cols 4..7 stay zero
    uint32_t w4f[4 * 64 * 4];   // W4 A-frags, [kt][lane] as uint4
    float    b1[HID], b2[HID], b3[HID];
    float    kk[RT * 4];        // K of current iter (for final combine)
};

__device__ __forceinline__ uint16_t f2bf(float f) {
    uint32_t u = __float_as_uint(f);
    return (uint16_t)((u + 0x7fffu + ((u >> 16) & 1u)) >> 16);
}

__device__ __forceinline__ uint32_t pk2(float a, float b) {
    __hip_bfloat162 h = __float22bfloat162_rn(float2{a, b});
    return *reinterpret_cast<uint32_t*>(&h);
}

// tanh = 1 - 2/(e^{2x}+1); 2 quarter-rate ops, NaN/inf-safe for our range.
__device__ __forceinline__ float tanh_fast(float x) {
    float e = __builtin_amdgcn_exp2f(x * 2.885390081777927f);  // e^{2x}
    return fmaf(-2.0f, __builtin_amdgcn_rcpf(e + 1.0f), 1.0f);
}

// dst = tanh(src @ W + bias), transposed MFMA (W^T as A from registers).
__device__ __forceinline__ void dense_mfma(
    const bf16x8 (&wf)[4][4], const float* __restrict__ bias,
    const uint16_t* __restrict__ src, uint16_t* __restrict__ dst,
    int wm, int wn, int ln, int g)
{
    f32x4 acc[4][2];
    #pragma unroll
    for (int mt = 0; mt < 4; ++mt) {
        f32x4 bs = *(const f32x4*)&bias[wm * 64 + mt * 16 + 4 * g];
        acc[mt][0] = bs;
        acc[mt][1] = bs;
    }
    const int r0 = wn * 32 + ln;
    #pragma unroll
    for (int kt = 0; kt < 4; ++kt) {
        bf16x8 bfr0 = *(const bf16x8*)&src[r0 * HSTR + kt * 32 + 8 * g];
        bf16x8 bfr1 = *(const bf16x8*)&src[(r0 + 16) * HSTR + kt * 32 + 8 * g];
        #pragma unroll
        for (int mt = 0; mt < 4; ++mt) {
            acc[mt][0] = __builtin_amdgcn_mfma_f32_16x16x32_bf16(wf[mt][kt], bfr0, acc[mt][0], 0, 0, 0);
            acc[mt][1] = __builtin_amdgcn_mfma_f32_16x16x32_bf16(wf[mt][kt], bfr1, acc[mt][1], 0, 0, 0);
        }
    }
    #pragma unroll
    for (int mt = 0; mt < 4; ++mt) {
        int hb = wm * 64 + mt * 16 + 4 * g;
        #pragma unroll
        for (int nt = 0; nt < 2; ++nt) {
            int r = wn * 32 + nt * 16 + ln;
            u32x2 p;
            p.x = pk2(tanh_fast(acc[mt][nt][0]), tanh_fast(acc[mt][nt][1]));
            p.y = pk2(tanh_fast(acc[mt][nt][2]), tanh_fast(acc[mt][nt][3]));
            *(u32x2*)&dst[r * HSTR + hb] = p;
        }
    }
}

__global__ __launch_bounds__(NT) void pinn_irk_mfma(
    const float* __restrict__ x0g,
    const float* __restrict__ w1g, const float* __restrict__ b1g,
    const float* __restrict__ w2g, const float* __restrict__ b2g,
    const float* __restrict__ w3g, const float* __restrict__ b3g,
    const float* __restrict__ w4g, const float* __restrict__ b4g,
    const float* __restrict__ l1g, const float* __restrict__ l2g,
    const float* __restrict__ l3g, const float* __restrict__ l4g,
    const float* __restrict__ alg, const float* __restrict__ beg,
    float* __restrict__ outg)
{
    __shared__ Smem S;
    const int t    = threadIdx.x;
    const int blk  = blockIdx.x;
    const int lane = t & 63;
    const int w    = t >> 6;        // wave 0..3
    const int wm   = w & 1;         // hid half (M)
    const int wn   = w >> 1;        // batch half (N)
    const int ln   = lane & 15;
    const int g    = lane >> 4;     // quad
    const bool owner = (g == 0);
    const int r_own  = w * 16 + ln; // row owned by this lane (if owner)

    // ---- uniform params -> SGPRs ----
    const float L0 = l1g[0], L1v = l2g[0], L2v = l3g[0], L3v = l4g[0];
    const float B40 = b4g[0], B41 = b4g[1], B42 = b4g[2], B43 = b4g[3];

    // ---- stage biases / zero xb pad ----
    if (t < HID) { S.b1[t] = b1g[t]; S.b2[t] = b2g[t]; S.b3[t] = b3g[t]; }
    {   // zero only cols 4..7 of xb (cols 0..3 written by owner lanes)
        int r = t >> 2, c = 4 + (t & 3);
        S.xb[r * 8 + c] = 0;
    }
    // ---- stage W4 A-frags into LDS: [kt][lane] ----
    {
        int kt = t >> 6, l = t & 63;
        int lns = l & 15, gs = l >> 4;
        uint32_t f[4];
        #pragma unroll
        for (int jj = 0; jj < 4; ++jj) {
            int k0 = kt * 32 + 8 * gs + 2 * jj;
            uint32_t lo = (lns < 4) ? (uint32_t)f2bf(w4g[k0 * 4 + lns]) : 0u;
            uint32_t hi = (lns < 4) ? (uint32_t)f2bf(w4g[(k0 + 1) * 4 + lns]) : 0u;
            f[jj] = lo | (hi << 16);
        }
        *(u32x4*)&S.w4f[t * 4] = (u32x4){f[0], f[1], f[2], f[3]};
    }

    // ---- owner-lane state: X0 and current X in registers; init xb ----
    float X0r[4] = {0.f, 0.f, 0.f, 0.f};
    float Xr[4]  = {0.f, 0.f, 0.f, 0.f};
    if (owner) {
        const float* xp = x0g + (blk * (RT / 4) + (r_own >> 2)) * 4;
        #pragma unroll
        for (int c = 0; c < 4; ++c) { X0r[c] = xp[c]; Xr[c] = X0r[c]; }
        u32x2 p;
        p.x = pk2(Xr[0], Xr[1]);
        p.y = pk2(Xr[2], Xr[3]);
        *(u32x2*)&S.xb[r_own * 8] = p;
    }

    // ---- weight fragments W1/W2/W3 into registers ----
    // A-frag of W^T: lane (ln,g), elem j -> W[k=kt*32+8g+j][m=wm*64+mt*16+ln]
    bf16x8 w1f[4], w2f[4][4], w3f[4][4];
    {
        const int mcol = wm * 64 + ln;
        #pragma unroll
        for (int mt = 0; mt < 4; ++mt) {
            bf16x8 f1;
            #pragma unroll
            for (int j = 0; j < 8; ++j) {
                int k = 8 * g + j;
                float v = (k < 4) ? w1g[k * HID + mcol + mt * 16] : 0.0f;
                f1[j] = (short)f2bf(v);
            }
            w1f[mt] = f1;
            #pragma unroll
            for (int kt = 0; kt < 4; ++kt) {
                bf16x8 f2, f3;
                #pragma unroll
                for (int j = 0; j < 8; ++j) {
                    int k = kt * 32 + 8 * g + j;
                    f2[j] = (short)f2bf(w2g[k * HID + mcol + mt * 16]);
                    f3[j] = (short)f2bf(w3g[k * HID + mcol + mt * 16]);
                }
                w2f[mt][kt] = f2;
                w3f[mt][kt] = f3;
            }
        }
    }
    __syncthreads();

    #pragma unroll 1
    for (int it = 0; it < NITER; ++it) {
        // ---- L1: hA = tanh(X @ W1 + b1), K padded 4->32 ----
        {
            f32x4 acc[4][2];
            #pragma unroll
            for (int mt = 0; mt < 4; ++mt) {
                f32x4 bs = *(const f32x4*)&S.b1[wm * 64 + mt * 16 + 4 * g];
                acc[mt][0] = bs;
                acc[mt][1] = bs;
            }
            bf16x8 bfr0 = {0,0,0,0,0,0,0,0}, bfr1 = {0,0,0,0,0,0,0,0};
            if (g == 0) {
                bfr0 = *(const bf16x8*)&S.xb[(wn * 32 + ln) * 8];
                bfr1 = *(const bf16x8*)&S.xb[(wn * 32 + 16 + ln) * 8];
            }
            #pragma unroll
            for (int mt = 0; mt < 4; ++mt) {
                acc[mt][0] = __builtin_amdgcn_mfma_f32_16x16x32_bf16(w1f[mt], bfr0, acc[mt][0], 0, 0, 0);
                acc[mt][1] = __builtin_amdgcn_mfma_f32_16x16x32_bf16(w1f[mt], bfr1, acc[mt][1], 0, 0, 0);
            }
            #pragma unroll
            for (int mt = 0; mt < 4; ++mt) {
                int hb = wm * 64 + mt * 16 + 4 * g;
                #pragma unroll
                for (int nt = 0; nt < 2; ++nt) {
                    int r = wn * 32 + nt * 16 + ln;
                    u32x2 p;
                    p.x = pk2(tanh_fast(acc[mt][nt][0]), tanh_fast(acc[mt][nt][1]));
                    p.y = pk2(tanh_fast(acc[mt][nt][2]), tanh_fast(acc[mt][nt][3]));
                    *(u32x2*)&S.hA[r * HSTR + hb] = p;
                }
            }
        }
        __syncthreads();

        // ---- L2 ----
        dense_mfma(w2f, S.b2, S.hA, S.hB, wm, wn, ln, g);
        __syncthreads();

        // ---- L3 ----
        dense_mfma(w3f, S.b3, S.hB, S.hA, wm, wn, ln, g);
        __syncthreads();

        // ---- L4 + K update + X update (owner lanes) ----
        {
            f32x4 acc = (f32x4){0.f, 0.f, 0.f, 0.f};
            #pragma unroll
            for (int kt = 0; kt < 4; ++kt) {
                bf16x8 wfr = *(const bf16x8*)&S.w4f[(kt * 64 + lane) * 4];
                bf16x8 bfr = *(const bf16x8*)&S.hA[r_own * HSTR + kt * 32 + 8 * g];
                acc = __builtin_amdgcn_mfma_f32_16x16x32_bf16(wfr, bfr, acc, 0, 0, 0);
            }
            if (owner) {
                float h0 = acc[0] + B40, h1 = acc[1] + B41;
                float h2 = acc[2] + B42, h3 = acc[3] + B43;
                float kv0 = -L0 * h2 - L1v * Xr[2];
                float kv1 = -L0 * h3 - L1v * Xr[3];
                float kv2 =  L2v * h0 + L3v * Xr[0];
                float kv3 =  L2v * h1 + L3v * Xr[1];
                *(f32x4*)&S.kk[r_own * 4] = (f32x4){kv0, kv1, kv2, kv3};
                // X_next = X0 + dt * K . alpha  (alpha rows i, cols c)
                #pragma unroll
                for (int c = 0; c < 4; ++c) {
                    float s = kv0 * alg[c] + kv1 * alg[4 + c]
                            + kv2 * alg[8 + c] + kv3 * alg[12 + c];
                    Xr[c] = fmaf(DT, s, X0r[c]);
                }
                u32x2 p;
                p.x = pk2(Xr[0], Xr[1]);
                p.y = pk2(Xr[2], Xr[3]);
                *(u32x2*)&S.xb[r_own * 8] = p;
            }
        }
        __syncthreads();
    }

    // ---- final combine: X1 = X0 + dt * sum_q beta_q K[:,q,:] ----
    if (t < RT) {
        int bb = t >> 2, i = t & 3;
        float s = beg[0] * S.kk[(bb * 4 + 0) * 4 + i]
                + beg[1] * S.kk[(bb * 4 + 1) * 4 + i]
                + beg[2] * S.kk[(bb * 4 + 2) * 4 + i]
                + beg[3] * S.kk[(bb * 4 + 3) * 4 + i];
        int bglob = blk * (RT / 4) + bb;
        outg[bglob * 4 + i] = x0g[bglob * 4 + i] + DT * s;
    }
}

extern "C" void kernel_launch(void* const* d_in, const int* in_sizes, int n_in,
                              void* d_out, int out_size, void* d_ws, size_t ws_size,
                              hipStream_t stream) {
    (void)in_sizes; (void)n_in; (void)d_ws; (void)ws_size; (void)out_size;

    const int n_rows = 65536 * 4;        // B * Q
    dim3 grid(n_rows / RT);              // 4096
    dim3 block(NT);

    pinn_irk_mfma<<<grid, block, 0, stream>>>(
        (const float*)d_in[0],
        (const float*)d_in[1],  (const float*)d_in[2],
        (const float*)d_in[3],  (const float*)d_in[4],
        (const float*)d_in[5],  (const float*)d_in[6],
        (const float*)d_in[7],  (const float*)d_in[8],
        (const float*)d_in[9],  (const float*)d_in[10],
        (const float*)d_in[11], (const float*)d_in[12],
        (const float*)d_in[13], (const float*)d_in[14],
        (float*)d_out);
}

// Round 5
// 407.251 us; speedup vs baseline: 10.2304x; 1.5159x over previous
//
#include <hip/hip_runtime.h>
#include <hip/hip_bf16.h>
#include <stdint.h>

#define HID   128
#define DT    0.1f
#define NITER 10
#define RT    64           // rows (b,q pairs) per block
#define NT    256          // 4 waves
#define HSTR  136          // H row stride in bf16 elems (odd multiple of 16B)

typedef __attribute__((ext_vector_type(8))) short bf16x8;   // MFMA A/B frag
typedef __attribute__((ext_vector_type(4))) float f32x4;    // MFMA C/D frag
typedef __attribute__((ext_vector_type(2))) unsigned int u32x2;
typedef __attribute__((ext_vector_type(4))) unsigned int u32x4;

struct alignas(16) Smem {
    uint16_t hA[RT * HSTR];     // activations [batch][hid] bf16
    uint16_t hB[RT * HSTR];
    uint16_t xb[RT * 8];        // X bf16 [row][8], cols 4..7 stay zero
    uint32_t w4f[4 * 64 * 4];   // W4 A-frags, [kt][lane] as uint4
    float    b1[HID], b2[HID], b3[HID];
    float    kk[RT * 4];        // K of current iter (for final combine)
};

__device__ __forceinline__ uint16_t f2bf(float f) {
    uint32_t u = __float_as_uint(f);
    return (uint16_t)((u + 0x7fffu + ((u >> 16) & 1u)) >> 16);
}

__device__ __forceinline__ uint32_t pk2(float a, float b) {
    __hip_bfloat162 h = __float22bfloat162_rn(float2{a, b});
    return *reinterpret_cast<uint32_t*>(&h);
}

// tanh = 1 - 2/(e^{2x}+1); 2 quarter-rate ops.
__device__ __forceinline__ float tanh_fast(float x) {
    float e = __builtin_amdgcn_exp2f(x * 2.885390081777927f);  // e^{2x}
    return fmaf(-2.0f, __builtin_amdgcn_rcpf(e + 1.0f), 1.0f);
}

// dst = tanh(src @ W + bias), transposed MFMA. Wave owns M-slice of 32
// (2 m-tiles), covers all 64 batch rows (4 n-tiles).
__device__ __forceinline__ void dense_mfma(
    const bf16x8 (&wf)[2][4], const float* __restrict__ bias,
    const uint16_t* __restrict__ src, uint16_t* __restrict__ dst,
    int w, int ln, int g)
{
    f32x4 acc[2][4];
    #pragma unroll
    for (int mt = 0; mt < 2; ++mt) {
        f32x4 bs = *(const f32x4*)&bias[w * 32 + mt * 16 + 4 * g];
        #pragma unroll
        for (int nt = 0; nt < 4; ++nt) acc[mt][nt] = bs;
    }
    #pragma unroll
    for (int kt = 0; kt < 4; ++kt) {
        bf16x8 bfr[4];
        #pragma unroll
        for (int nt = 0; nt < 4; ++nt)
            bfr[nt] = *(const bf16x8*)&src[(nt * 16 + ln) * HSTR + kt * 32 + 8 * g];
        #pragma unroll
        for (int mt = 0; mt < 2; ++mt)
            #pragma unroll
            for (int nt = 0; nt < 4; ++nt)
                acc[mt][nt] = __builtin_amdgcn_mfma_f32_16x16x32_bf16(wf[mt][kt], bfr[nt], acc[mt][nt], 0, 0, 0);
    }
    #pragma unroll
    for (int mt = 0; mt < 2; ++mt) {
        int hb = w * 32 + mt * 16 + 4 * g;
        #pragma unroll
        for (int nt = 0; nt < 4; ++nt) {
            int r = nt * 16 + ln;
            u32x2 p;
            p.x = pk2(tanh_fast(acc[mt][nt][0]), tanh_fast(acc[mt][nt][1]));
            p.y = pk2(tanh_fast(acc[mt][nt][2]), tanh_fast(acc[mt][nt][3]));
            *(u32x2*)&dst[r * HSTR + hb] = p;
        }
    }
}

__global__ __launch_bounds__(NT, 3) void pinn_irk_mfma(
    const float* __restrict__ x0g,
    const float* __restrict__ w1g, const float* __restrict__ b1g,
    const float* __restrict__ w2g, const float* __restrict__ b2g,
    const float* __restrict__ w3g, const float* __restrict__ b3g,
    const float* __restrict__ w4g, const float* __restrict__ b4g,
    const float* __restrict__ l1g, const float* __restrict__ l2g,
    const float* __restrict__ l3g, const float* __restrict__ l4g,
    const float* __restrict__ alg, const float* __restrict__ beg,
    float* __restrict__ outg)
{
    __shared__ Smem S;
    const int t    = threadIdx.x;
    const int blk  = blockIdx.x;
    const int lane = t & 63;
    const int w    = t >> 6;        // wave 0..3: owns hid slice [w*32, w*32+32)
    const int ln   = lane & 15;
    const int g    = lane >> 4;     // quad
    const bool owner = (g == 0);
    const int r_own  = w * 16 + ln; // batch row owned by this lane (if owner)

    // ---- uniform params -> SGPRs ----
    const float L0 = l1g[0], L1v = l2g[0], L2v = l3g[0], L3v = l4g[0];
    const float B40 = b4g[0], B41 = b4g[1], B42 = b4g[2], B43 = b4g[3];

    // ---- stage biases / zero xb pad ----
    if (t < HID) { S.b1[t] = b1g[t]; S.b2[t] = b2g[t]; S.b3[t] = b3g[t]; }
    {   // zero cols 4..7 of xb (cols 0..3 written by owner lanes)
        int r = t >> 2, c = 4 + (t & 3);
        S.xb[r * 8 + c] = 0;
    }
    // ---- stage W4 A-frags into LDS: [kt][lane] ----
    {
        int kt = t >> 6, l = t & 63;
        int lns = l & 15, gs = l >> 4;
        uint32_t f[4];
        #pragma unroll
        for (int jj = 0; jj < 4; ++jj) {
            int k0 = kt * 32 + 8 * gs + 2 * jj;
            uint32_t lo = (lns < 4) ? (uint32_t)f2bf(w4g[k0 * 4 + lns]) : 0u;
            uint32_t hi = (lns < 4) ? (uint32_t)f2bf(w4g[(k0 + 1) * 4 + lns]) : 0u;
            f[jj] = lo | (hi << 16);
        }
        *(u32x4*)&S.w4f[t * 4] = (u32x4){f[0], f[1], f[2], f[3]};
    }

    // ---- owner-lane state: X0 / X in registers; init xb ----
    float X0r[4] = {0.f, 0.f, 0.f, 0.f};
    float Xr[4]  = {0.f, 0.f, 0.f, 0.f};
    if (owner) {
        const float* xp = x0g + (blk * (RT / 4) + (r_own >> 2)) * 4;
        #pragma unroll
        for (int c = 0; c < 4; ++c) { X0r[c] = xp[c]; Xr[c] = X0r[c]; }
        u32x2 p;
        p.x = pk2(Xr[0], Xr[1]);
        p.y = pk2(Xr[2], Xr[3]);
        *(u32x2*)&S.xb[r_own * 8] = p;
    }

    // ---- weight fragments W1/W2/W3 (M-slice of 32 per wave) ----
    // A-frag of W^T: lane (ln,g), elem j -> W[k=kt*32+8g+j][m=w*32+mt*16+ln]
    bf16x8 w1f[2], w2f[2][4], w3f[2][4];
    {
        const int mcol = w * 32 + ln;
        #pragma unroll
        for (int mt = 0; mt < 2; ++mt) {
            bf16x8 f1;
            #pragma unroll
            for (int j = 0; j < 8; ++j) {
                int k = 8 * g + j;
                float v = (k < 4) ? w1g[k * HID + mcol + mt * 16] : 0.0f;
                f1[j] = (short)f2bf(v);
            }
            w1f[mt] = f1;
            #pragma unroll
            for (int kt = 0; kt < 4; ++kt) {
                bf16x8 f2, f3;
                #pragma unroll
                for (int j = 0; j < 8; ++j) {
                    int k = kt * 32 + 8 * g + j;
                    f2[j] = (short)f2bf(w2g[k * HID + mcol + mt * 16]);
                    f3[j] = (short)f2bf(w3g[k * HID + mcol + mt * 16]);
                }
                w2f[mt][kt] = f2;
                w3f[mt][kt] = f3;
            }
        }
    }
    __syncthreads();

    #pragma unroll 1
    for (int it = 0; it < NITER; ++it) {
        // ---- L1: hA = tanh(X @ W1 + b1), K padded 4->32 ----
        {
            f32x4 acc[2][4];
            #pragma unroll
            for (int mt = 0; mt < 2; ++mt) {
                f32x4 bs = *(const f32x4*)&S.b1[w * 32 + mt * 16 + 4 * g];
                #pragma unroll
                for (int nt = 0; nt < 4; ++nt) acc[mt][nt] = bs;
            }
            bf16x8 bfr[4];
            #pragma unroll
            for (int nt = 0; nt < 4; ++nt) bfr[nt] = (bf16x8){0,0,0,0,0,0,0,0};
            if (g == 0) {
                #pragma unroll
                for (int nt = 0; nt < 4; ++nt)
                    bfr[nt] = *(const bf16x8*)&S.xb[(nt * 16 + ln) * 8];
            }
            #pragma unroll
            for (int mt = 0; mt < 2; ++mt)
                #pragma unroll
                for (int nt = 0; nt < 4; ++nt)
                    acc[mt][nt] = __builtin_amdgcn_mfma_f32_16x16x32_bf16(w1f[mt], bfr[nt], acc[mt][nt], 0, 0, 0);
            #pragma unroll
            for (int mt = 0; mt < 2; ++mt) {
                int hb = w * 32 + mt * 16 + 4 * g;
                #pragma unroll
                for (int nt = 0; nt < 4; ++nt) {
                    int r = nt * 16 + ln;
                    u32x2 p;
                    p.x = pk2(tanh_fast(acc[mt][nt][0]), tanh_fast(acc[mt][nt][1]));
                    p.y = pk2(tanh_fast(acc[mt][nt][2]), tanh_fast(acc[mt][nt][3]));
                    *(u32x2*)&S.hA[r * HSTR + hb] = p;
                }
            }
        }
        __syncthreads();

        // ---- L2 ----
        dense_mfma(w2f, S.b2, S.hA, S.hB, w, ln, g);
        __syncthreads();

        // ---- L3 ----
        dense_mfma(w3f, S.b3, S.hB, S.hA, w, ln, g);
        __syncthreads();

        // ---- L4 + K update + X update (owner lanes) ----
        {
            f32x4 acc = (f32x4){0.f, 0.f, 0.f, 0.f};
            #pragma unroll
            for (int kt = 0; kt < 4; ++kt) {
                bf16x8 wfr = *(const bf16x8*)&S.w4f[(kt * 64 + lane) * 4];
                bf16x8 bfr = *(const bf16x8*)&S.hA[r_own * HSTR + kt * 32 + 8 * g];
                acc = __builtin_amdgcn_mfma_f32_16x16x32_bf16(wfr, bfr, acc, 0, 0, 0);
            }
            if (owner) {
                float h0 = acc[0] + B40, h1 = acc[1] + B41;
                float h2 = acc[2] + B42, h3 = acc[3] + B43;
                float kv0 = -L0 * h2 - L1v * Xr[2];
                float kv1 = -L0 * h3 - L1v * Xr[3];
                float kv2 =  L2v * h0 + L3v * Xr[0];
                float kv3 =  L2v * h1 + L3v * Xr[1];
                *(f32x4*)&S.kk[r_own * 4] = (f32x4){kv0, kv1, kv2, kv3};
                #pragma unroll
                for (int c = 0; c < 4; ++c) {
                    float s = kv0 * alg[c] + kv1 * alg[4 + c]
                            + kv2 * alg[8 + c] + kv3 * alg[12 + c];
                    Xr[c] = fmaf(DT, s, X0r[c]);
                }
                u32x2 p;
                p.x = pk2(Xr[0], Xr[1]);
                p.y = pk2(Xr[2], Xr[3]);
                *(u32x2*)&S.xb[r_own * 8] = p;
            }
        }
        __syncthreads();
    }

    // ---- final combine: X1 = X0 + dt * sum_q beta_q K[:,q,:] ----
    if (t < RT) {
        int bb = t >> 2, i = t & 3;
        float s = beg[0] * S.kk[(bb * 4 + 0) * 4 + i]
                + beg[1] * S.kk[(bb * 4 + 1) * 4 + i]
                + beg[2] * S.kk[(bb * 4 + 2) * 4 + i]
                + beg[3] * S.kk[(bb * 4 + 3) * 4 + i];
        int bglob = blk * (RT / 4) + bb;
        outg[bglob * 4 + i] = x0g[bglob * 4 + i] + DT * s;
    }
}

extern "C" void kernel_launch(void* const* d_in, const int* in_sizes, int n_in,
                              void* d_out, int out_size, void* d_ws, size_t ws_size,
                              hipStream_t stream) {
    (void)in_sizes; (void)n_in; (void)d_ws; (void)ws_size; (void)out_size;

    const int n_rows = 65536 * 4;        // B * Q
    dim3 grid(n_rows / RT);              // 4096
    dim3 block(NT);

    pinn_irk_mfma<<<grid, block, 0, stream>>>(
        (const float*)d_in[0],
        (const float*)d_in[1],  (const float*)d_in[2],
        (const float*)d_in[3],  (const float*)d_in[4],
        (const float*)d_in[5],  (const float*)d_in[6],
        (const float*)d_in[7],  (const float*)d_in[8],
        (const float*)d_in[9],  (const float*)d_in[10],
        (const float*)d_in[11], (const float*)d_in[12],
        (const float*)d_in[13], (const float*)d_in[14],
        (float*)d_out);
}